// Round 7
// baseline (814.461 us; speedup 1.0000x reference)
//
#include <hip/hip_runtime.h>
#include <stdint.h>

// Problem constants
#define NN    50000
#define EE    800000
#define IN_C  128
#define ED_C  64
#define HID_C 256
#define BB    128
#define KK    1000
#define G1_C  128
#define NV    50176   // NN padded to 196*256 for scan

// R6/R7/R8: three different k_edge2 structures all ~180us with FETCH=286MB
// invariant; R8 falsifier fired (occupancy 21->42%, dur flat) => not latency.
// Diagnosis: ea gather in sorted order = random 256B DRAM reads of 205MB
// (L3-thrashed) -> page-activation bound ~1.8TB/s. R9 (this): payload sort.
// k_scatter2 relocates ea rows (bf16, 128B) into dst-sorted EA[]; k_edge3
// reads EA streaming, MFMA A-frags direct from global (no staging, 2 barriers).
// EA=102.4MB aliases h0b/h1b/h2b; needs ws>=136MB -> runtime branch with
// byte-identical R8 fallback when ws is small.

typedef __attribute__((ext_vector_type(8))) short bfrag;   // 8 x bf16
typedef __attribute__((ext_vector_type(4))) float f4acc;   // 4 x f32 acc

__device__ __forceinline__ unsigned short f2bs(float f){   // f32 -> bf16 (RNE)
  unsigned u = __float_as_uint(f);
  return (unsigned short)((u + 0x7fffu + ((u >> 16) & 1u)) >> 16);
}
__device__ __forceinline__ float bs2f(unsigned short s){
  return __uint_as_float(((unsigned)s) << 16);
}

__device__ __forceinline__ void atomicMaxFloat(float* addr, float val){
  int old = __float_as_int(*addr);
  while (__int_as_float(old) < val){
    int assumed = old;
    old = atomicCAS((int*)addr, assumed, __float_as_int(val));
    if (old == assumed) break;
  }
}

// ---------------- prep: cast+transpose weights to bf16 (Wt[n][k] = W[k][n]) --
__global__ __launch_bounds__(256) void k_prep(
    const float* __restrict__ We, const float* __restrict__ W1,
    const float* __restrict__ W2, const float* __restrict__ Wg1,
    unsigned short* __restrict__ Wet, unsigned short* __restrict__ W1t,
    unsigned short* __restrict__ W2t, unsigned short* __restrict__ Wg1t)
{
  int i = blockIdx.x * 256 + threadIdx.x;
  if (i < 128 * 64){ int c = i >> 6, k = i & 63;  Wet[i]  = f2bs(We[k * 128 + c]); }
  if (i < 256 * 128){ int n = i >> 7, k = i & 127; W1t[i]  = f2bs(W1[k * 256 + n]); }
  if (i < 256 * 256){ int n = i >> 8, k = i & 255; W2t[i]  = f2bs(W2[k * 256 + n]); }
  if (i < 128 * 256){ int n = i >> 8, k = i & 255; Wg1t[i] = f2bs(Wg1[k * 128 + n]); }
}

// ---------------- init: zero agg/cnt/fill/aux/denom/pooled, gmax=-1e30 ----
__global__ __launch_bounds__(256) void k_init(float* __restrict__ agg,
                                              int* __restrict__ cnt,
                                              int* __restrict__ fill,
                                              int* __restrict__ aux,
                                              float* __restrict__ gmax,
                                              float* __restrict__ denom,
                                              float* __restrict__ pooled){
  size_t i = (size_t)blockIdx.x * 256 + threadIdx.x;
  if (i < (size_t)NN * IN_C) agg[i] = 0.f;
  if (i < NV){ cnt[i] = 0; fill[i] = 0; }
  if (i < 256) aux[i] = 0;
  if (i < BB){ gmax[i] = -1e30f; denom[i] = 0.f; }
  if (i < BB * HID_C) pooled[i] = 0.f;
}

// ---------------- counting sort by dst: hist -> scan -> scatter ----------
__global__ __launch_bounds__(256) void k_hist(const int* __restrict__ ei,
                                              int* __restrict__ cnt){
  int e = blockIdx.x * 256 + threadIdx.x;
  if (e < EE) atomicAdd(&cnt[ei[EE + e]], 1);
}

__global__ __launch_bounds__(256) void k_scan1(const int* __restrict__ cnt,
                                               int* __restrict__ off,
                                               int* __restrict__ aux){
  __shared__ int s[256];
  int t = threadIdx.x, i = blockIdx.x * 256 + t;
  int val = cnt[i];
  s[t] = val; __syncthreads();
#pragma unroll
  for (int o = 1; o < 256; o <<= 1){
    int v = (t >= o) ? s[t - o] : 0;
    __syncthreads();
    s[t] += v;
    __syncthreads();
  }
  off[i] = s[t] - val;
  if (t == 255) aux[blockIdx.x] = s[255];
}

__global__ __launch_bounds__(256) void k_scan2(int* __restrict__ aux){
  __shared__ int s[256];
  int t = threadIdx.x;
  int val = aux[t];
  s[t] = val; __syncthreads();
#pragma unroll
  for (int o = 1; o < 256; o <<= 1){
    int v = (t >= o) ? s[t - o] : 0;
    __syncthreads();
    s[t] += v;
    __syncthreads();
  }
  aux[t] = s[t] - val;
}

__global__ __launch_bounds__(256) void k_scan3(int* __restrict__ off,
                                               const int* __restrict__ aux){
  int i = blockIdx.x * 256 + threadIdx.x;
  off[i] += aux[blockIdx.x];
}

// ---- fallback scatter: 16B index records only ----
__global__ __launch_bounds__(256) void k_scatter(const int* __restrict__ ei,
                                                 const int* __restrict__ off,
                                                 int* __restrict__ fill,
                                                 uint4* __restrict__ sorted){
  int e = blockIdx.x * 256 + threadIdx.x;
  if (e < EE){
    int s = ei[e], d = ei[EE + e];
    int pos = off[d] + atomicAdd(&fill[d], 1);
    sorted[pos] = make_uint4((unsigned)e, (unsigned)s, (unsigned)d, 0u);
  }
}

// ---- big-path scatter: relocate ea payload (bf16) into sorted order ----
// Reads ea streaming (205MB), writes EA random 128B (102MB) + sd 8B.
__global__ __launch_bounds__(256) void k_scatter2(
    const int* __restrict__ ei, const float* __restrict__ ea,
    const int* __restrict__ off, int* __restrict__ fill,
    uint2* __restrict__ sd, unsigned short* __restrict__ EA)
{
  int e = blockIdx.x * 256 + threadIdx.x;
  if (e >= EE) return;
  int s = ei[e], d = ei[EE + e];
  int pos = off[d] + atomicAdd(&fill[d], 1);
  sd[pos] = make_uint2((unsigned)s, (unsigned)d);
  const float4* s4 = (const float4*)(ea + (size_t)e * ED_C);
  uint2* d2 = (uint2*)(EA + (size_t)pos * ED_C);
#pragma unroll
  for (int j = 0; j < 16; ++j){
    float4 v = s4[j];
    d2[j] = make_uint2((unsigned)f2bs(v.x) | ((unsigned)f2bs(v.y) << 16),
                       (unsigned)f2bs(v.z) | ((unsigned)f2bs(v.w) << 16));
  }
}

// ---------------- edge stage, fallback (R8): 64-row tile, run-list) -----
__global__ __launch_bounds__(256, 4) void k_edge2(
    const float* __restrict__ x, const uint4* __restrict__ sorted,
    const float* __restrict__ edge_attr,
    const unsigned short* __restrict__ Wet, const float* __restrict__ be,
    float* __restrict__ agg)
{
  __shared__ float msgS[64 * 132];
  __shared__ uint4 sE[64];
  __shared__ int runStart[66];
  __shared__ int nRunsS;
  unsigned short* eaS = (unsigned short*)msgS;

  const int tid = threadIdx.x;
  const int e0 = blockIdx.x * 64;
  if (tid < 64) sE[tid] = sorted[e0 + tid];
  __syncthreads();

  const int lane = tid & 63, wv = tid >> 6;
  const int q = lane >> 4, l15 = lane & 15;
  const int g0 = wv * 16;

  const int xrow = g0 + (lane >> 2);
  const int xc0 = (lane & 3) * 32;
  const float* xptr = x + (size_t)((int)sE[xrow].y) * IN_C + xc0;
  float4 xr[8];
#pragma unroll
  for (int j = 0; j < 8; ++j) xr[j] = *(const float4*)(xptr + j * 4);

#pragma unroll
  for (int t = 0; t < 4; ++t){
    int f4 = t * 256 + tid;
    int er = f4 >> 4;
    int kk = (f4 & 15) * 4;
    int eid = (int)sE[er].x;
    const float4 v = *(const float4*)(edge_attr + (size_t)eid * ED_C + kk);
    unsigned p0 = (unsigned)f2bs(v.x) | ((unsigned)f2bs(v.y) << 16);
    unsigned p1 = (unsigned)f2bs(v.z) | ((unsigned)f2bs(v.w) << 16);
    *(uint2*)&eaS[er * 72 + kk] = make_uint2(p0, p1);
  }

  if (tid < 64){
    bool flag = (tid == 0) || ((int)sE[tid].z != (int)sE[tid - 1].z);
    unsigned long long m = __ballot(flag);
    int pre = __popcll(m & ((1ull << tid) - 1ull));
    if ((m >> tid) & 1ull) runStart[pre] = tid;
    if (tid == 0){
      int nr = __popcll(m);
      nRunsS = nr;
      runStart[nr] = 64;
    }
  }
  __syncthreads();

  f4acc acc[8];
  const f4acc zz = {0.f, 0.f, 0.f, 0.f};
#pragma unroll
  for (int nt = 0; nt < 8; ++nt) acc[nt] = zz;

#pragma unroll
  for (int ks = 0; ks < 2; ++ks){
    bfrag a = *(const bfrag*)&eaS[(g0 + l15) * 72 + ks * 32 + q * 8];
#pragma unroll
    for (int nt = 0; nt < 8; ++nt){
      int c = nt * 16 + l15;
      bfrag b = *(const bfrag*)(Wet + c * ED_C + ks * 32 + q * 8);
      acc[nt] = __builtin_amdgcn_mfma_f32_16x16x32_bf16(a, b, acc[nt], 0, 0, 0);
    }
  }

  float bev[8];
#pragma unroll
  for (int nt = 0; nt < 8; ++nt) bev[nt] = be[nt * 16 + l15];

  __syncthreads();

#pragma unroll
  for (int nt = 0; nt < 8; ++nt){
    int c = nt * 16 + l15;
#pragma unroll
    for (int r = 0; r < 4; ++r)
      msgS[(g0 + q * 4 + r) * 132 + c] = acc[nt][r] + bev[nt];
  }

  {
    float* mr = &msgS[xrow * 132 + xc0];
#pragma unroll
    for (int j = 0; j < 8; ++j){
      float4 w = *(float4*)(mr + j * 4);
      const float4 v = xr[j];
      w.x = fmaxf(w.x + v.x, 0.f);
      w.y = fmaxf(w.y + v.y, 0.f);
      w.z = fmaxf(w.z + v.z, 0.f);
      w.w = fmaxf(w.w + v.w, 0.f);
      *(float4*)(mr + j * 4) = w;
    }
  }
  __syncthreads();

  {
    const int col = tid & 127;
    const int h = tid >> 7;
    const int nR = nRunsS;
    for (int i = h; i < nR; i += 2){
      int s = runStart[i], e = runStart[i + 1];
      int dst = (int)sE[s].z;
      float run = 0.f;
      for (int r = s; r < e; ++r) run += msgS[r * 132 + col];
      size_t a = (size_t)dst * IN_C + col;
      if (s == 0 || e == 64) atomicAdd(&agg[a], run);
      else                   agg[a] = run;
    }
  }
}

// ---------------- edge stage, big path: streaming EA, no staging ---------
// A-frags load direct from global EA (block's contiguous 8KB chunk).
// Barriers: S1 (sE) | S2 (msgS final + run list). Occupancy 4 blk/CU.
__global__ __launch_bounds__(256, 4) void k_edge3(
    const float* __restrict__ x, const uint2* __restrict__ sd,
    const unsigned short* __restrict__ EA,
    const unsigned short* __restrict__ Wet, const float* __restrict__ be,
    float* __restrict__ agg)
{
  __shared__ float msgS[64 * 132];
  __shared__ uint2 sE[64];
  __shared__ int runStart[66];
  __shared__ int nRunsS;

  const int tid = threadIdx.x;
  if (tid < 64) sE[tid] = sd[(size_t)blockIdx.x * 64 + tid];
  __syncthreads();                           // S1: sE ready

  const int lane = tid & 63, wv = tid >> 6;
  const int q = lane >> 4, l15 = lane & 15;
  const int g0 = wv * 16;

  // x prefetch: lane owns row g0+(lane>>2), 32-col quarter
  const int xrow = g0 + (lane >> 2);
  const int xc0 = (lane & 3) * 32;
  const float* xptr = x + (size_t)((int)sE[xrow].x) * IN_C + xc0;
  float4 xr[8];
#pragma unroll
  for (int j = 0; j < 8; ++j) xr[j] = *(const float4*)(xptr + j * 4);

  // run list: single-wave ballot on dst
  if (tid < 64){
    bool flag = (tid == 0) || (sE[tid].y != sE[tid - 1].y);
    unsigned long long m = __ballot(flag);
    int pre = __popcll(m & ((1ull << tid) - 1ull));
    if ((m >> tid) & 1ull) runStart[pre] = tid;
    if (tid == 0){
      int nr = __popcll(m);
      nRunsS = nr;
      runStart[nr] = 64;
    }
  }

  // MFMA: A-frags straight from global EA (streaming, bf16 already)
  const unsigned short* EAb = EA + (size_t)blockIdx.x * 64 * ED_C;
  f4acc acc[8];
  const f4acc zz = {0.f, 0.f, 0.f, 0.f};
#pragma unroll
  for (int nt = 0; nt < 8; ++nt) acc[nt] = zz;

#pragma unroll
  for (int ks = 0; ks < 2; ++ks){
    bfrag a = *(const bfrag*)(EAb + (size_t)(g0 + l15) * ED_C + ks * 32 + q * 8);
#pragma unroll
    for (int nt = 0; nt < 8; ++nt){
      int c = nt * 16 + l15;
      bfrag b = *(const bfrag*)(Wet + c * ED_C + ks * 32 + q * 8);
      acc[nt] = __builtin_amdgcn_mfma_f32_16x16x32_bf16(a, b, acc[nt], 0, 0, 0);
    }
  }

  float bev[8];
#pragma unroll
  for (int nt = 0; nt < 8; ++nt) bev[nt] = be[nt * 16 + l15];

  // msgS = acc + be (fragment layout; wave writes only its 16 rows)
#pragma unroll
  for (int nt = 0; nt < 8; ++nt){
    int c = nt * 16 + l15;
#pragma unroll
    for (int r = 0; r < 4; ++r)
      msgS[(g0 + q * 4 + r) * 132 + c] = acc[nt][r] + bev[nt];
  }

  // fold x in (same wave's rows; lgkmcnt-ordered, no block barrier)
  {
    float* mr = &msgS[xrow * 132 + xc0];
#pragma unroll
    for (int j = 0; j < 8; ++j){
      float4 w = *(float4*)(mr + j * 4);
      const float4 v = xr[j];
      w.x = fmaxf(w.x + v.x, 0.f);
      w.y = fmaxf(w.y + v.y, 0.f);
      w.z = fmaxf(w.z + v.z, 0.f);
      w.w = fmaxf(w.w + v.w, 0.f);
      *(float4*)(mr + j * 4) = w;
    }
  }
  __syncthreads();                           // S2: msgS + run list final

  // per-column run walk; interior runs -> store, boundary -> atomic
  {
    const int col = tid & 127;
    const int h = tid >> 7;
    const int nR = nRunsS;
    for (int i = h; i < nR; i += 2){
      int s = runStart[i], e = runStart[i + 1];
      int dst = (int)sE[s].y;
      float run = 0.f;
      for (int r = s; r < e; ++r) run += msgS[r * 132 + col];
      size_t a = (size_t)dst * IN_C + col;
      if (s == 0 || e == 64) atomicAdd(&agg[a], run);
      else                   agg[a] = run;
    }
  }
}

// ---------------- h0 = agg + x -> bf16 ----------------
__global__ __launch_bounds__(256) void k_h0(const float* __restrict__ agg,
                                            const float* __restrict__ x,
                                            unsigned short* __restrict__ h0b){
  int i = blockIdx.x * 256 + threadIdx.x;
  if (i < NN * IN_C) h0b[i] = f2bs(agg[i] + x[i]);
}

// ---------------- MFMA GEMM with LDS-staged fragments --------------------
template<int K, bool RELU, bool OF32, bool OB16>
__global__ __launch_bounds__(256) void k_gemm(
    const unsigned short* __restrict__ A, const unsigned short* __restrict__ Wt,
    const float* __restrict__ bias, float* __restrict__ outf,
    unsigned short* __restrict__ outb, int M, int Ntot)
{
  __shared__ unsigned short aS[64 * 40];
  __shared__ unsigned short bS[128 * 40];
  const int tid = threadIdx.x;
  const int lane = tid & 63, wv = tid >> 6;
  const int wi = wv >> 1, wj = wv & 1;
  const int q = lane >> 4, l15 = lane & 15;
  const int mb0 = blockIdx.x * 64;
  const int nb0 = blockIdx.y * 128;
  const int arow = tid >> 2, achk = tid & 3;

  f4acc acc[2][4];
  const f4acc zz = {0.f, 0.f, 0.f, 0.f};
#pragma unroll
  for (int mt = 0; mt < 2; ++mt)
#pragma unroll
    for (int nt = 0; nt < 4; ++nt) acc[mt][nt] = zz;

  for (int ks = 0; ks < K / 32; ++ks){
    {
      int m = mb0 + arow; if (m >= M) m = M - 1;
      const uint4 v = *(const uint4*)(A + (size_t)m * K + ks * 32 + achk * 8);
      *(uint4*)&aS[arow * 40 + achk * 8] = v;
    }
#pragma unroll
    for (int i = 0; i < 2; ++i){
      int idx = i * 256 + tid;
      int row = idx >> 2, chk = idx & 3;
      const uint4 v = *(const uint4*)(Wt + (size_t)(nb0 + row) * K + ks * 32 + chk * 8);
      *(uint4*)&bS[row * 40 + chk * 8] = v;
    }
    __syncthreads();
    bfrag a[2], b[4];
#pragma unroll
    for (int mt = 0; mt < 2; ++mt)
      a[mt] = *(const bfrag*)&aS[(wi * 32 + mt * 16 + l15) * 40 + q * 8];
#pragma unroll
    for (int nt = 0; nt < 4; ++nt)
      b[nt] = *(const bfrag*)&bS[(wj * 64 + nt * 16 + l15) * 40 + q * 8];
#pragma unroll
    for (int mt = 0; mt < 2; ++mt)
#pragma unroll
      for (int nt = 0; nt < 4; ++nt)
        acc[mt][nt] = __builtin_amdgcn_mfma_f32_16x16x32_bf16(a[mt], b[nt], acc[mt][nt], 0, 0, 0);
    __syncthreads();
  }

  const int mb = mb0 + wi * 32;
  const int nb = nb0 + wj * 64;
#pragma unroll
  for (int nt = 0; nt < 4; ++nt){
    int c = nb + nt * 16 + l15;
    float bv = bias[c];
#pragma unroll
    for (int mt = 0; mt < 2; ++mt){
#pragma unroll
      for (int r = 0; r < 4; ++r){
        int m = mb + mt * 16 + q * 4 + r;
        if (m < M){
          float v = acc[mt][nt][r] + bv;
          if (RELU) v = v > 0.f ? v : 0.f;
          if (OF32) outf[(size_t)m * Ntot + c] = v;
          if (OB16) outb[(size_t)m * Ntot + c] = f2bs(v);
        }
      }
    }
  }
}

// ---------------- gate2: gate[r] = g1[r,:128].Wg2 + bg2 (wave/row) -------
__global__ __launch_bounds__(256) void k_gate2(const float* __restrict__ g1,
                                               const float* __restrict__ Wg2,
                                               const float* __restrict__ bg2,
                                               float* __restrict__ gate, int nrows){
  const int lane = threadIdx.x & 63, wv = threadIdx.x >> 6;
  const float2 w2 = *(const float2*)(Wg2 + lane * 2);
  const float bg = bg2[0];
  for (int r = blockIdx.x * 4 + wv; r < nrows; r += gridDim.x * 4){
    const float2 a2 = *(const float2*)(g1 + (size_t)r * G1_C + lane * 2);
    float p = a2.x * w2.x + a2.y * w2.y;
#pragma unroll
    for (int off = 32; off > 0; off >>= 1) p += __shfl_down(p, off);
    if (lane == 0) gate[r] = p + bg;
  }
}

// ---------------- segment max (batch sorted; block pre-reduce) ----------
__global__ __launch_bounds__(256) void k_gmax(const float* __restrict__ gate,
                                              const int* __restrict__ batch,
                                              float* __restrict__ gmax, int nrows){
  __shared__ float red[256];
  const int tid = threadIdx.x;
  const int n0 = blockIdx.x * 256;
  const int n = n0 + tid;
  const int nlast = (n0 + 255 < nrows) ? n0 + 255 : nrows - 1;
  const int bmin = batch[n0], bmax = batch[nlast];
  float val = -3e38f; int b = bmax;
  if (n < nrows){ b = batch[n]; val = gate[n]; }
  for (int bb = bmin; bb <= bmax; ++bb){
    red[tid] = (b == bb) ? val : -3e38f;
    __syncthreads();
    for (int s = 128; s > 0; s >>= 1){
      if (tid < s) red[tid] = fmaxf(red[tid], red[tid + s]);
      __syncthreads();
    }
    if (tid == 0 && red[0] > -1e37f) atomicMaxFloat(&gmax[bb], red[0]);
    __syncthreads();
  }
}

// ---------------- a = exp(gate - gmax[b]); denom[b] += a ----------------
__global__ __launch_bounds__(256) void k_expsum(const float* __restrict__ gate,
                                                const int* __restrict__ batch,
                                                const float* __restrict__ gmax,
                                                float* __restrict__ aexp,
                                                float* __restrict__ denom, int nrows){
  __shared__ float red[256];
  const int tid = threadIdx.x;
  const int n0 = blockIdx.x * 256;
  const int n = n0 + tid;
  const int nlast = (n0 + 255 < nrows) ? n0 + 255 : nrows - 1;
  const int bmin = batch[n0], bmax = batch[nlast];
  float val = 0.f; int b = bmax;
  if (n < nrows){
    b = batch[n];
    val = expf(gate[n] - gmax[b]);
    aexp[n] = val;
  }
  for (int bb = bmin; bb <= bmax; ++bb){
    red[tid] = (b == bb) ? val : 0.f;
    __syncthreads();
    for (int s = 128; s > 0; s >>= 1){
      if (tid < s) red[tid] += red[tid + s];
      __syncthreads();
    }
    if (tid == 0 && red[0] != 0.f) atomicAdd(&denom[bb], red[0]);
    __syncthreads();
  }
}

// ---------------- pooled[b] += (a/denom[b]) * h2[n] ----------------
__global__ __launch_bounds__(256) void k_pool(const unsigned short* __restrict__ h2b,
                                              const float* __restrict__ aexp,
                                              const float* __restrict__ denom,
                                              const int* __restrict__ batch,
                                              float* __restrict__ pooled, int nrows){
  const int c = threadIdx.x;
  const int n0 = blockIdx.x * 256;
  int n1 = n0 + 256; if (n1 > nrows) n1 = nrows;
  float acc = 0.f;
  int curb = batch[n0];
  for (int n = n0; n < n1; ++n){
    int b = batch[n];
    if (b != curb){
      atomicAdd(&pooled[(size_t)curb * HID_C + c], acc);
      acc = 0.f; curb = b;
    }
    float wgt = aexp[n] / denom[b];
    acc = fmaf(wgt, bs2f(h2b[(size_t)n * HID_C + c]), acc);
  }
  atomicAdd(&pooled[(size_t)curb * HID_C + c], acc);
}

// ---------------- head: logits = pooled @ Wh + bh ----------------
__global__ __launch_bounds__(256) void k_head(const float* __restrict__ pooled,
                                              const float* __restrict__ Wh,
                                              const float* __restrict__ bh,
                                              float* __restrict__ out_logits,
                                              float* __restrict__ out_pooled){
  __shared__ float p[HID_C];
  const int b = blockIdx.x, t = threadIdx.x;
  float pv = pooled[(size_t)b * HID_C + t];
  p[t] = pv;
  out_pooled[(size_t)b * HID_C + t] = pv;
  __syncthreads();
  for (int c = t; c < KK; c += 256){
    float acc = bh[c];
#pragma unroll 8
    for (int k = 0; k < HID_C; ++k)
      acc = fmaf(p[k], Wh[k * KK + c], acc);
    out_logits[(size_t)b * KK + c] = acc;
  }
}

extern "C" void kernel_launch(void* const* d_in, const int* in_sizes, int n_in,
                              void* d_out, int out_size, void* d_ws, size_t ws_size,
                              hipStream_t stream) {
  const float* x   = (const float*)d_in[0];
  const int*   ei  = (const int*)d_in[1];
  const float* ea  = (const float*)d_in[2];
  const int*   batch = (const int*)d_in[3];
  const float* We  = (const float*)d_in[4];
  const float* be  = (const float*)d_in[5];
  const float* W1  = (const float*)d_in[6];
  const float* b1  = (const float*)d_in[7];
  const float* W2  = (const float*)d_in[8];
  const float* b2  = (const float*)d_in[9];
  const float* Wg1 = (const float*)d_in[10];
  const float* bg1 = (const float*)d_in[11];
  const float* Wg2 = (const float*)d_in[12];
  const float* bg2 = (const float*)d_in[13];
  const float* Wh  = (const float*)d_in[14];
  const float* bh  = (const float*)d_in[15];

  float* out_logits = (float*)d_out;
  float* out_pooled = out_logits + (size_t)BB * KK;

  // common f32 region
  float* agg    = (float*)d_ws;                    // N*128 (g1f alias later)
  float* gate   = agg   + (size_t)NN * IN_C;       // N
  float* aexp   = gate  + NN;                      // N
  float* gmax   = aexp  + NN;                      // B
  float* denom  = gmax  + BB;                      // B
  float* pooled = denom + BB;                      // B*256
  float* fend   = pooled + (size_t)BB * HID_C;     // 16B-aligned
  float* g1f = agg;                                // alias: agg dead after k_h0

  const size_t NEED_BIG = 136000000ULL;            // ~135.82MB computed layout

  if (ws_size >= NEED_BIG){
    // ---- BIG layout: weights | sd | scan | EA (aliases h0b/h1b/h2b) ----
    unsigned short* Wet  = (unsigned short*)fend;  // 128*64
    unsigned short* W1t  = Wet + 128 * 64;
    unsigned short* W2t  = W1t + 256 * 128;
    unsigned short* Wg1t = W2t + 256 * 256;
    unsigned short* wend = Wg1t + 128 * 256;       // byte off 26,410,624 (8B ok)
    uint2* sd = (uint2*)wend;                      // EE*8 = 6.4MB
    int* cnt  = (int*)(sd + EE);                   // NV
    int* off  = cnt + NV;
    int* fill = off + NV;
    int* aux  = fill + NV;                         // 256
    size_t o = (size_t)((char*)(aux + 256) - (char*)d_ws);
    o = (o + 15) & ~(size_t)15;
    unsigned short* h0b = (unsigned short*)((char*)d_ws + o);
    unsigned short* EA  = h0b;                     // EE*64 bf16 = 102.4MB
    unsigned short* h1b = h0b + (size_t)NN * IN_C;
    unsigned short* h2b = h1b + (size_t)NN * HID_C;

    k_prep<<<256, 256, 0, stream>>>(We, W1, W2, Wg1, Wet, W1t, W2t, Wg1t);
    k_init<<<(NN * IN_C + 255) / 256, 256, 0, stream>>>(agg, cnt, fill, aux, gmax, denom, pooled);
    k_hist   <<<(EE + 255) / 256, 256, 0, stream>>>(ei, cnt);
    k_scan1  <<<NV / 256, 256, 0, stream>>>(cnt, off, aux);
    k_scan2  <<<1, 256, 0, stream>>>(aux);
    k_scan3  <<<NV / 256, 256, 0, stream>>>(off, aux);
    k_scatter2<<<(EE + 255) / 256, 256, 0, stream>>>(ei, ea, off, fill, sd, EA);
    k_edge3<<<EE / 64, 256, 0, stream>>>(x, sd, EA, Wet, be, agg);
    k_h0<<<(NN * IN_C + 255) / 256, 256, 0, stream>>>(agg, x, h0b);
    k_gemm<128, true,  false, true ><<<dim3(782, 2), 256, 0, stream>>>(h0b, W1t, b1, (float*)0, h1b, NN, HID_C);
    k_gemm<256, false, false, true ><<<dim3(782, 2), 256, 0, stream>>>(h1b, W2t, b2, (float*)0, h2b, NN, HID_C);
    k_gemm<256, true,  true,  false><<<dim3(782, 1), 256, 0, stream>>>(h2b, Wg1t, bg1, g1f, (unsigned short*)0, NN, G1_C);
    k_gate2<<<3125, 256, 0, stream>>>(g1f, Wg2, bg2, gate, NN);
    k_gmax  <<<(NN + 255) / 256, 256, 0, stream>>>(gate, batch, gmax, NN);
    k_expsum<<<(NN + 255) / 256, 256, 0, stream>>>(gate, batch, gmax, aexp, denom, NN);
    k_pool  <<<(NN + 255) / 256, 256, 0, stream>>>(h2b, aexp, denom, batch, pooled, NN);
    k_head<<<BB, 256, 0, stream>>>(pooled, Wh, bh, out_logits, out_pooled);
  } else {
    // ---- FALLBACK: exact R8 layout/path ----
    unsigned short* h0b  = (unsigned short*)fend;    // N*128 bf16
    unsigned short* h1b  = h0b + (size_t)NN * IN_C;  // N*256 bf16 (25.6MB)
    unsigned short* h2b  = h1b + (size_t)NN * HID_C; // N*256 bf16
    unsigned short* Wet  = h2b + (size_t)NN * HID_C; // 128*64
    unsigned short* W1t  = Wet + 128 * 64;
    unsigned short* W2t  = W1t + 256 * 128;
    unsigned short* Wg1t = W2t + 256 * 256;
    uint4* sorted = (uint4*)h1b;                     // EE * 16B
    int* cnt  = (int*)(sorted + EE);                 // NV
    int* off  = cnt + NV;                            // NV
    int* fill = off + NV;                            // NV
    int* aux  = fill + NV;                           // 256

    k_prep<<<256, 256, 0, stream>>>(We, W1, W2, Wg1, Wet, W1t, W2t, Wg1t);
    k_init<<<(NN * IN_C + 255) / 256, 256, 0, stream>>>(agg, cnt, fill, aux, gmax, denom, pooled);
    k_hist   <<<(EE + 255) / 256, 256, 0, stream>>>(ei, cnt);
    k_scan1  <<<NV / 256, 256, 0, stream>>>(cnt, off, aux);
    k_scan2  <<<1, 256, 0, stream>>>(aux);
    k_scan3  <<<NV / 256, 256, 0, stream>>>(off, aux);
    k_scatter<<<(EE + 255) / 256, 256, 0, stream>>>(ei, off, fill, sorted);
    k_edge2<<<EE / 64, 256, 0, stream>>>(x, sorted, ea, Wet, be, agg);
    k_h0<<<(NN * IN_C + 255) / 256, 256, 0, stream>>>(agg, x, h0b);
    k_gemm<128, true,  false, true ><<<dim3(782, 2), 256, 0, stream>>>(h0b, W1t, b1, (float*)0, h1b, NN, HID_C);
    k_gemm<256, false, false, true ><<<dim3(782, 2), 256, 0, stream>>>(h1b, W2t, b2, (float*)0, h2b, NN, HID_C);
    k_gemm<256, true,  true,  false><<<dim3(782, 1), 256, 0, stream>>>(h2b, Wg1t, bg1, g1f, (unsigned short*)0, NN, G1_C);
    k_gate2<<<3125, 256, 0, stream>>>(g1f, Wg2, bg2, gate, NN);
    k_gmax  <<<(NN + 255) / 256, 256, 0, stream>>>(gate, batch, gmax, NN);
    k_expsum<<<(NN + 255) / 256, 256, 0, stream>>>(gate, batch, gmax, aexp, denom, NN);
    k_pool  <<<(NN + 255) / 256, 256, 0, stream>>>(h2b, aexp, denom, batch, pooled, NN);
    k_head<<<BB, 256, 0, stream>>>(pooled, Wh, bh, out_logits, out_pooled);
  }
}

// Round 8
// 739.817 us; speedup vs baseline: 1.1009x; 1.1009x over previous
//
#include <hip/hip_runtime.h>
#include <stdint.h>

// Problem constants
#define NN    50000
#define EE    800000
#define IN_C  128
#define ED_C  64
#define HID_C 256
#define BB    128
#define KK    1000
#define G1_C  128
#define NV    50176   // NN padded to 196*256 for scan

// R6-R8: three edge structures all ~180us. R9 payload-sort: k_edge3 (EA
// streaming) only 167us => ea gather was NOT the bound; scatter2 cost 64us
// net loss. Invariant: edge kernel runs at ~3.3-3.7 TB/s total FABRIC
// (L2-miss) traffic; dominant term is the x[src] gather: 800K x 512B =
// 410MB logical (L3-resident, invisible in FETCH). R10 (this):
//  - revert payload sort (16B-record scatter, R8 edge path)
//  - pre-cast x -> bf16 xb (12.8MB, streaming ~7us); edge gathers 256B/row
//    => x fabric bytes halve 410->205MB. h0 still uses f32 x.

typedef __attribute__((ext_vector_type(8))) short bfrag;   // 8 x bf16
typedef __attribute__((ext_vector_type(4))) float f4acc;   // 4 x f32 acc

__device__ __forceinline__ unsigned short f2bs(float f){   // f32 -> bf16 (RNE)
  unsigned u = __float_as_uint(f);
  return (unsigned short)((u + 0x7fffu + ((u >> 16) & 1u)) >> 16);
}
__device__ __forceinline__ float bs2f(unsigned short s){
  return __uint_as_float(((unsigned)s) << 16);
}

__device__ __forceinline__ void atomicMaxFloat(float* addr, float val){
  int old = __float_as_int(*addr);
  while (__int_as_float(old) < val){
    int assumed = old;
    old = atomicCAS((int*)addr, assumed, __float_as_int(val));
    if (old == assumed) break;
  }
}

// ---------------- prep: cast+transpose weights to bf16 (Wt[n][k] = W[k][n]) --
__global__ __launch_bounds__(256) void k_prep(
    const float* __restrict__ We, const float* __restrict__ W1,
    const float* __restrict__ W2, const float* __restrict__ Wg1,
    unsigned short* __restrict__ Wet, unsigned short* __restrict__ W1t,
    unsigned short* __restrict__ W2t, unsigned short* __restrict__ Wg1t)
{
  int i = blockIdx.x * 256 + threadIdx.x;
  if (i < 128 * 64){ int c = i >> 6, k = i & 63;  Wet[i]  = f2bs(We[k * 128 + c]); }
  if (i < 256 * 128){ int n = i >> 7, k = i & 127; W1t[i]  = f2bs(W1[k * 256 + n]); }
  if (i < 256 * 256){ int n = i >> 8, k = i & 255; W2t[i]  = f2bs(W2[k * 256 + n]); }
  if (i < 128 * 256){ int n = i >> 8, k = i & 255; Wg1t[i] = f2bs(Wg1[k * 128 + n]); }
}

// ---------------- xb = bf16(x): streaming cast, 4 elems/thread ----------
__global__ __launch_bounds__(256) void k_xb(const float* __restrict__ x,
                                            unsigned short* __restrict__ xb){
  int i = blockIdx.x * 256 + threadIdx.x;
  if (i < NN * IN_C / 4){
    const float4 v = ((const float4*)x)[i];
    ushort4 o;
    o.x = f2bs(v.x); o.y = f2bs(v.y); o.z = f2bs(v.z); o.w = f2bs(v.w);
    ((ushort4*)xb)[i] = o;
  }
}

// ---------------- init: zero agg/cnt/fill/aux/denom/pooled, gmax=-1e30 ----
__global__ __launch_bounds__(256) void k_init(float* __restrict__ agg,
                                              int* __restrict__ cnt,
                                              int* __restrict__ fill,
                                              int* __restrict__ aux,
                                              float* __restrict__ gmax,
                                              float* __restrict__ denom,
                                              float* __restrict__ pooled){
  size_t i = (size_t)blockIdx.x * 256 + threadIdx.x;
  if (i < (size_t)NN * IN_C) agg[i] = 0.f;
  if (i < NV){ cnt[i] = 0; fill[i] = 0; }
  if (i < 256) aux[i] = 0;
  if (i < BB){ gmax[i] = -1e30f; denom[i] = 0.f; }
  if (i < BB * HID_C) pooled[i] = 0.f;
}

// ---------------- counting sort by dst: hist -> scan -> scatter ----------
__global__ __launch_bounds__(256) void k_hist(const int* __restrict__ ei,
                                              int* __restrict__ cnt){
  int e = blockIdx.x * 256 + threadIdx.x;
  if (e < EE) atomicAdd(&cnt[ei[EE + e]], 1);
}

__global__ __launch_bounds__(256) void k_scan1(const int* __restrict__ cnt,
                                               int* __restrict__ off,
                                               int* __restrict__ aux){
  __shared__ int s[256];
  int t = threadIdx.x, i = blockIdx.x * 256 + t;
  int val = cnt[i];
  s[t] = val; __syncthreads();
#pragma unroll
  for (int o = 1; o < 256; o <<= 1){
    int v = (t >= o) ? s[t - o] : 0;
    __syncthreads();
    s[t] += v;
    __syncthreads();
  }
  off[i] = s[t] - val;
  if (t == 255) aux[blockIdx.x] = s[255];
}

__global__ __launch_bounds__(256) void k_scan2(int* __restrict__ aux){
  __shared__ int s[256];
  int t = threadIdx.x;
  int val = aux[t];
  s[t] = val; __syncthreads();
#pragma unroll
  for (int o = 1; o < 256; o <<= 1){
    int v = (t >= o) ? s[t - o] : 0;
    __syncthreads();
    s[t] += v;
    __syncthreads();
  }
  aux[t] = s[t] - val;
}

__global__ __launch_bounds__(256) void k_scan3(int* __restrict__ off,
                                               const int* __restrict__ aux){
  int i = blockIdx.x * 256 + threadIdx.x;
  off[i] += aux[blockIdx.x];
}

__global__ __launch_bounds__(256) void k_scatter(const int* __restrict__ ei,
                                                 const int* __restrict__ off,
                                                 int* __restrict__ fill,
                                                 uint4* __restrict__ sorted){
  int e = blockIdx.x * 256 + threadIdx.x;
  if (e < EE){
    int s = ei[e], d = ei[EE + e];
    int pos = off[d] + atomicAdd(&fill[d], 1);
    sorted[pos] = make_uint4((unsigned)e, (unsigned)s, (unsigned)d, 0u);
  }
}

// ---------------- edge stage (MFMA, dst-sorted, run-list reduce) ---------
// Block = 256 thr / 4 waves; tile = 64 sorted slots x 128 channels.
// x gathered from bf16 xb (256B/row, half the fabric bytes of f32).
__global__ __launch_bounds__(256, 4) void k_edge2(
    const unsigned short* __restrict__ xb, const uint4* __restrict__ sorted,
    const float* __restrict__ edge_attr,
    const unsigned short* __restrict__ Wet, const float* __restrict__ be,
    float* __restrict__ agg)
{
  __shared__ float msgS[64 * 132];           // 33.8KB; aliased by ea staging
  __shared__ uint4 sE[64];
  __shared__ int runStart[66];
  __shared__ int nRunsS;
  unsigned short* eaS = (unsigned short*)msgS;   // 64*72 shorts

  const int tid = threadIdx.x;
  const int e0 = blockIdx.x * 64;
  if (tid < 64) sE[tid] = sorted[e0 + tid];
  __syncthreads();                           // S1: sE ready

  const int lane = tid & 63, wv = tid >> 6;
  const int q = lane >> 4, l15 = lane & 15;
  const int g0 = wv * 16;

  // ---- x prefetch (bf16): lane owns row g0+(lane>>2), 32-col quarter ----
  const int xrow = g0 + (lane >> 2);
  const int xc0 = (lane & 3) * 32;
  const unsigned short* xptr = xb + (size_t)((int)sE[xrow].y) * IN_C + xc0;
  uint4 xr[4];                               // 32 bf16 = 64B
#pragma unroll
  for (int j = 0; j < 4; ++j) xr[j] = *(const uint4*)(xptr + j * 8);

  // ---- edge_attr -> bf16 staging (64 rows x 64ch; 4 float4/thread) ----
#pragma unroll
  for (int t = 0; t < 4; ++t){
    int f4 = t * 256 + tid;
    int er = f4 >> 4;
    int kk = (f4 & 15) * 4;
    int eid = (int)sE[er].x;
    const float4 v = *(const float4*)(edge_attr + (size_t)eid * ED_C + kk);
    unsigned p0 = (unsigned)f2bs(v.x) | ((unsigned)f2bs(v.y) << 16);
    unsigned p1 = (unsigned)f2bs(v.z) | ((unsigned)f2bs(v.w) << 16);
    *(uint2*)&eaS[er * 72 + kk] = make_uint2(p0, p1);
  }

  // ---- run list: single wave (64 slots) ballot + prefix ----
  if (tid < 64){
    bool flag = (tid == 0) || ((int)sE[tid].z != (int)sE[tid - 1].z);
    unsigned long long m = __ballot(flag);
    int pre = __popcll(m & ((1ull << tid) - 1ull));
    if ((m >> tid) & 1ull) runStart[pre] = tid;
    if (tid == 0){
      int nr = __popcll(m);
      nRunsS = nr;
      runStart[nr] = 64;
    }
  }
  __syncthreads();                           // S2: eaS + run list ready

  f4acc acc[8];
  const f4acc zz = {0.f, 0.f, 0.f, 0.f};
#pragma unroll
  for (int nt = 0; nt < 8; ++nt) acc[nt] = zz;

#pragma unroll
  for (int ks = 0; ks < 2; ++ks){
    bfrag a = *(const bfrag*)&eaS[(g0 + l15) * 72 + ks * 32 + q * 8];
#pragma unroll
    for (int nt = 0; nt < 8; ++nt){
      int c = nt * 16 + l15;
      bfrag b = *(const bfrag*)(Wet + c * ED_C + ks * 32 + q * 8);
      acc[nt] = __builtin_amdgcn_mfma_f32_16x16x32_bf16(a, b, acc[nt], 0, 0, 0);
    }
  }

  float bev[8];
#pragma unroll
  for (int nt = 0; nt < 8; ++nt) bev[nt] = be[nt * 16 + l15];

  __syncthreads();                           // S3: eaS reads done, msgS writable

  // ---- msgS = acc + be (fragment layout; wave writes only its 16 rows) ----
#pragma unroll
  for (int nt = 0; nt < 8; ++nt){
    int c = nt * 16 + l15;
#pragma unroll
    for (int r = 0; r < 4; ++r)
      msgS[(g0 + q * 4 + r) * 132 + c] = acc[nt][r] + bev[nt];
  }

  // ---- fold bf16 x in (same wave's rows; lgkmcnt-ordered) ----
  {
    float* mr = &msgS[xrow * 132 + xc0];
#pragma unroll
    for (int jj = 0; jj < 4; ++jj){          // per uint4 = 8 cols
      const uint4 u = xr[jj];
      float4 w0 = *(float4*)(mr + jj * 8);
      float4 w1 = *(float4*)(mr + jj * 8 + 4);
      w0.x = fmaxf(w0.x + __uint_as_float(u.x << 16), 0.f);
      w0.y = fmaxf(w0.y + __uint_as_float(u.x & 0xffff0000u), 0.f);
      w0.z = fmaxf(w0.z + __uint_as_float(u.y << 16), 0.f);
      w0.w = fmaxf(w0.w + __uint_as_float(u.y & 0xffff0000u), 0.f);
      w1.x = fmaxf(w1.x + __uint_as_float(u.z << 16), 0.f);
      w1.y = fmaxf(w1.y + __uint_as_float(u.z & 0xffff0000u), 0.f);
      w1.z = fmaxf(w1.z + __uint_as_float(u.w << 16), 0.f);
      w1.w = fmaxf(w1.w + __uint_as_float(u.w & 0xffff0000u), 0.f);
      *(float4*)(mr + jj * 8) = w0;
      *(float4*)(mr + jj * 8 + 4) = w1;
    }
  }
  __syncthreads();                           // S5: messages final

  // ---- per-column run walk: interior -> store, boundary -> atomic ----
  {
    const int col = tid & 127;
    const int h = tid >> 7;
    const int nR = nRunsS;
    for (int i = h; i < nR; i += 2){
      int s = runStart[i], e = runStart[i + 1];
      int dst = (int)sE[s].z;
      float run = 0.f;
      for (int r = s; r < e; ++r) run += msgS[r * 132 + col];
      size_t a = (size_t)dst * IN_C + col;
      if (s == 0 || e == 64) atomicAdd(&agg[a], run);
      else                   agg[a] = run;
    }
  }
}

// ---------------- h0 = agg + x -> bf16 (f32 x here) ----------------
__global__ __launch_bounds__(256) void k_h0(const float* __restrict__ agg,
                                            const float* __restrict__ x,
                                            unsigned short* __restrict__ h0b){
  int i = blockIdx.x * 256 + threadIdx.x;
  if (i < NN * IN_C) h0b[i] = f2bs(agg[i] + x[i]);
}

// ---------------- MFMA GEMM with LDS-staged fragments --------------------
template<int K, bool RELU, bool OF32, bool OB16>
__global__ __launch_bounds__(256) void k_gemm(
    const unsigned short* __restrict__ A, const unsigned short* __restrict__ Wt,
    const float* __restrict__ bias, float* __restrict__ outf,
    unsigned short* __restrict__ outb, int M, int Ntot)
{
  __shared__ unsigned short aS[64 * 40];
  __shared__ unsigned short bS[128 * 40];
  const int tid = threadIdx.x;
  const int lane = tid & 63, wv = tid >> 6;
  const int wi = wv >> 1, wj = wv & 1;
  const int q = lane >> 4, l15 = lane & 15;
  const int mb0 = blockIdx.x * 64;
  const int nb0 = blockIdx.y * 128;
  const int arow = tid >> 2, achk = tid & 3;

  f4acc acc[2][4];
  const f4acc zz = {0.f, 0.f, 0.f, 0.f};
#pragma unroll
  for (int mt = 0; mt < 2; ++mt)
#pragma unroll
    for (int nt = 0; nt < 4; ++nt) acc[mt][nt] = zz;

  for (int ks = 0; ks < K / 32; ++ks){
    {
      int m = mb0 + arow; if (m >= M) m = M - 1;
      const uint4 v = *(const uint4*)(A + (size_t)m * K + ks * 32 + achk * 8);
      *(uint4*)&aS[arow * 40 + achk * 8] = v;
    }
#pragma unroll
    for (int i = 0; i < 2; ++i){
      int idx = i * 256 + tid;
      int row = idx >> 2, chk = idx & 3;
      const uint4 v = *(const uint4*)(Wt + (size_t)(nb0 + row) * K + ks * 32 + chk * 8);
      *(uint4*)&bS[row * 40 + chk * 8] = v;
    }
    __syncthreads();
    bfrag a[2], b[4];
#pragma unroll
    for (int mt = 0; mt < 2; ++mt)
      a[mt] = *(const bfrag*)&aS[(wi * 32 + mt * 16 + l15) * 40 + q * 8];
#pragma unroll
    for (int nt = 0; nt < 4; ++nt)
      b[nt] = *(const bfrag*)&bS[(wj * 64 + nt * 16 + l15) * 40 + q * 8];
#pragma unroll
    for (int mt = 0; mt < 2; ++mt)
#pragma unroll
      for (int nt = 0; nt < 4; ++nt)
        acc[mt][nt] = __builtin_amdgcn_mfma_f32_16x16x32_bf16(a[mt], b[nt], acc[mt][nt], 0, 0, 0);
    __syncthreads();
  }

  const int mb = mb0 + wi * 32;
  const int nb = nb0 + wj * 64;
#pragma unroll
  for (int nt = 0; nt < 4; ++nt){
    int c = nb + nt * 16 + l15;
    float bv = bias[c];
#pragma unroll
    for (int mt = 0; mt < 2; ++mt){
#pragma unroll
      for (int r = 0; r < 4; ++r){
        int m = mb + mt * 16 + q * 4 + r;
        if (m < M){
          float v = acc[mt][nt][r] + bv;
          if (RELU) v = v > 0.f ? v : 0.f;
          if (OF32) outf[(size_t)m * Ntot + c] = v;
          if (OB16) outb[(size_t)m * Ntot + c] = f2bs(v);
        }
      }
    }
  }
}

// ---------------- gate2: gate[r] = g1[r,:128].Wg2 + bg2 (wave/row) -------
__global__ __launch_bounds__(256) void k_gate2(const float* __restrict__ g1,
                                               const float* __restrict__ Wg2,
                                               const float* __restrict__ bg2,
                                               float* __restrict__ gate, int nrows){
  const int lane = threadIdx.x & 63, wv = threadIdx.x >> 6;
  const float2 w2 = *(const float2*)(Wg2 + lane * 2);
  const float bg = bg2[0];
  for (int r = blockIdx.x * 4 + wv; r < nrows; r += gridDim.x * 4){
    const float2 a2 = *(const float2*)(g1 + (size_t)r * G1_C + lane * 2);
    float p = a2.x * w2.x + a2.y * w2.y;
#pragma unroll
    for (int off = 32; off > 0; off >>= 1) p += __shfl_down(p, off);
    if (lane == 0) gate[r] = p + bg;
  }
}

// ---------------- segment max (batch sorted; block pre-reduce) ----------
__global__ __launch_bounds__(256) void k_gmax(const float* __restrict__ gate,
                                              const int* __restrict__ batch,
                                              float* __restrict__ gmax, int nrows){
  __shared__ float red[256];
  const int tid = threadIdx.x;
  const int n0 = blockIdx.x * 256;
  const int n = n0 + tid;
  const int nlast = (n0 + 255 < nrows) ? n0 + 255 : nrows - 1;
  const int bmin = batch[n0], bmax = batch[nlast];
  float val = -3e38f; int b = bmax;
  if (n < nrows){ b = batch[n]; val = gate[n]; }
  for (int bb = bmin; bb <= bmax; ++bb){
    red[tid] = (b == bb) ? val : -3e38f;
    __syncthreads();
    for (int s = 128; s > 0; s >>= 1){
      if (tid < s) red[tid] = fmaxf(red[tid], red[tid + s]);
      __syncthreads();
    }
    if (tid == 0 && red[0] > -1e37f) atomicMaxFloat(&gmax[bb], red[0]);
    __syncthreads();
  }
}

// ---------------- a = exp(gate - gmax[b]); denom[b] += a ----------------
__global__ __launch_bounds__(256) void k_expsum(const float* __restrict__ gate,
                                                const int* __restrict__ batch,
                                                const float* __restrict__ gmax,
                                                float* __restrict__ aexp,
                                                float* __restrict__ denom, int nrows){
  __shared__ float red[256];
  const int tid = threadIdx.x;
  const int n0 = blockIdx.x * 256;
  const int n = n0 + tid;
  const int nlast = (n0 + 255 < nrows) ? n0 + 255 : nrows - 1;
  const int bmin = batch[n0], bmax = batch[nlast];
  float val = 0.f; int b = bmax;
  if (n < nrows){
    b = batch[n];
    val = expf(gate[n] - gmax[b]);
    aexp[n] = val;
  }
  for (int bb = bmin; bb <= bmax; ++bb){
    red[tid] = (b == bb) ? val : 0.f;
    __syncthreads();
    for (int s = 128; s > 0; s >>= 1){
      if (tid < s) red[tid] += red[tid + s];
      __syncthreads();
    }
    if (tid == 0 && red[0] != 0.f) atomicAdd(&denom[bb], red[0]);
    __syncthreads();
  }
}

// ---------------- pooled[b] += (a/denom[b]) * h2[n] ----------------
__global__ __launch_bounds__(256) void k_pool(const unsigned short* __restrict__ h2b,
                                              const float* __restrict__ aexp,
                                              const float* __restrict__ denom,
                                              const int* __restrict__ batch,
                                              float* __restrict__ pooled, int nrows){
  const int c = threadIdx.x;
  const int n0 = blockIdx.x * 256;
  int n1 = n0 + 256; if (n1 > nrows) n1 = nrows;
  float acc = 0.f;
  int curb = batch[n0];
  for (int n = n0; n < n1; ++n){
    int b = batch[n];
    if (b != curb){
      atomicAdd(&pooled[(size_t)curb * HID_C + c], acc);
      acc = 0.f; curb = b;
    }
    float wgt = aexp[n] / denom[b];
    acc = fmaf(wgt, bs2f(h2b[(size_t)n * HID_C + c]), acc);
  }
  atomicAdd(&pooled[(size_t)curb * HID_C + c], acc);
}

// ---------------- head: logits = pooled @ Wh + bh ----------------
__global__ __launch_bounds__(256) void k_head(const float* __restrict__ pooled,
                                              const float* __restrict__ Wh,
                                              const float* __restrict__ bh,
                                              float* __restrict__ out_logits,
                                              float* __restrict__ out_pooled){
  __shared__ float p[HID_C];
  const int b = blockIdx.x, t = threadIdx.x;
  float pv = pooled[(size_t)b * HID_C + t];
  p[t] = pv;
  out_pooled[(size_t)b * HID_C + t] = pv;
  __syncthreads();
  for (int c = t; c < KK; c += 256){
    float acc = bh[c];
#pragma unroll 8
    for (int k = 0; k < HID_C; ++k)
      acc = fmaf(p[k], Wh[k * KK + c], acc);
    out_logits[(size_t)b * KK + c] = acc;
  }
}

extern "C" void kernel_launch(void* const* d_in, const int* in_sizes, int n_in,
                              void* d_out, int out_size, void* d_ws, size_t ws_size,
                              hipStream_t stream) {
  const float* x   = (const float*)d_in[0];
  const int*   ei  = (const int*)d_in[1];
  const float* ea  = (const float*)d_in[2];
  const int*   batch = (const int*)d_in[3];
  const float* We  = (const float*)d_in[4];
  const float* be  = (const float*)d_in[5];
  const float* W1  = (const float*)d_in[6];
  const float* b1  = (const float*)d_in[7];
  const float* W2  = (const float*)d_in[8];
  const float* b2  = (const float*)d_in[9];
  const float* Wg1 = (const float*)d_in[10];
  const float* bg1 = (const float*)d_in[11];
  const float* Wg2 = (const float*)d_in[12];
  const float* bg2 = (const float*)d_in[13];
  const float* Wh  = (const float*)d_in[14];
  const float* bh  = (const float*)d_in[15];

  float* out_logits = (float*)d_out;
  float* out_pooled = out_logits + (size_t)BB * KK;

  // ws layout: f32 region | h0b | h1b (aliased by sort scratch) | h2b |
  // weights | xb   (total ~103.2MB; ws >= 136MB verified in R9 big path)
  float* agg    = (float*)d_ws;                    // N*128 (g1f alias later)
  float* gate   = agg   + (size_t)NN * IN_C;       // N
  float* aexp   = gate  + NN;                      // N
  float* gmax   = aexp  + NN;                      // B
  float* denom  = gmax  + BB;                      // B
  float* pooled = denom + BB;                      // B*256
  float* fend   = pooled + (size_t)BB * HID_C;     // 16B-aligned
  unsigned short* h0b  = (unsigned short*)fend;    // N*128 bf16
  unsigned short* h1b  = h0b + (size_t)NN * IN_C;  // N*256 bf16 (25.6MB)
  unsigned short* h2b  = h1b + (size_t)NN * HID_C; // N*256 bf16
  unsigned short* Wet  = h2b + (size_t)NN * HID_C; // 128*64
  unsigned short* W1t  = Wet + 128 * 64;
  unsigned short* W2t  = W1t + 256 * 128;
  unsigned short* Wg1t = W2t + 256 * 256;
  unsigned short* xb   = Wg1t + 128 * 256;         // N*128 bf16 (12.8MB)
  float* g1f = agg;                                // alias: agg dead after k_h0
  // sort scratch aliases h1b region (dead until gemm1): 12.8MB + 0.6MB < 25.6MB
  uint4* sorted = (uint4*)h1b;                     // EE * 16B
  int* cnt  = (int*)(sorted + EE);                 // NV
  int* off  = cnt + NV;                            // NV
  int* fill = off + NV;                            // NV
  int* aux  = fill + NV;                           // 256

  k_prep<<<256, 256, 0, stream>>>(We, W1, W2, Wg1, Wet, W1t, W2t, Wg1t);
  k_xb<<<(NN * IN_C / 4 + 255) / 256, 256, 0, stream>>>(x, xb);
  k_init<<<(NN * IN_C + 255) / 256, 256, 0, stream>>>(agg, cnt, fill, aux, gmax, denom, pooled);
  // counting sort by dst
  k_hist   <<<(EE + 255) / 256, 256, 0, stream>>>(ei, cnt);
  k_scan1  <<<NV / 256, 256, 0, stream>>>(cnt, off, aux);
  k_scan2  <<<1, 256, 0, stream>>>(aux);
  k_scan3  <<<NV / 256, 256, 0, stream>>>(off, aux);
  k_scatter<<<(EE + 255) / 256, 256, 0, stream>>>(ei, off, fill, sorted);
  // edge projection + message + run-list segmented-reduce scatter
  k_edge2<<<EE / 64, 256, 0, stream>>>(xb, sorted, ea, Wet, be, agg);
  k_h0<<<(NN * IN_C + 255) / 256, 256, 0, stream>>>(agg, x, h0b);
  // MLP + gate GEMMs (sort scratch dead from here; h1b reused)
  k_gemm<128, true,  false, true ><<<dim3(782, 2), 256, 0, stream>>>(h0b, W1t, b1, (float*)0, h1b, NN, HID_C);
  k_gemm<256, false, false, true ><<<dim3(782, 2), 256, 0, stream>>>(h1b, W2t, b2, (float*)0, h2b, NN, HID_C);
  k_gemm<256, true,  true,  false><<<dim3(782, 1), 256, 0, stream>>>(h2b, Wg1t, bg1, g1f, (unsigned short*)0, NN, G1_C);
  k_gate2<<<3125, 256, 0, stream>>>(g1f, Wg2, bg2, gate, NN);
  k_gmax  <<<(NN + 255) / 256, 256, 0, stream>>>(gate, batch, gmax, NN);
  k_expsum<<<(NN + 255) / 256, 256, 0, stream>>>(gate, batch, gmax, aexp, denom, NN);
  k_pool  <<<(NN + 255) / 256, 256, 0, stream>>>(h2b, aexp, denom, batch, pooled, NN);
  k_head<<<BB, 256, 0, stream>>>(pooled, Wh, bh, out_logits, out_pooled);
}

// Round 9
// 666.862 us; speedup vs baseline: 1.2213x; 1.1094x over previous
//
#include <hip/hip_runtime.h>
#include <stdint.h>

// Problem constants
#define NN    50000
#define EE    800000
#define IN_C  128
#define ED_C  64
#define HID_C 256
#define BB    128
#define KK    1000
#define G1_C  128
#define NV    50176   // NN padded to 196*256 for scan

// R6-R10 history: edge kernel has a ~160us byte-insensitive floor (occupancy,
// bytes, streaming-vs-gather all falsified as single factors). R10 total 740
// with k_edge2=161 => ~580us hidden in the other 16 dispatches (all <161).
// R11 (this): attack the hidden pool, edge path UNTOUCHED:
//  - k_pool: 32-row chunks (1563 blocks) vs 256-row serial (196 blocks)
//  - gemm3+gate2 fused (shuffle row-reduce epilogue) -> no g1f roundtrip
//  - k_gmax/k_expsum: wave-shuffle reduce, barriers 16 -> 2 per segment
//  - k_prep+k_xb+k_init merged into k_setup

typedef __attribute__((ext_vector_type(8))) short bfrag;   // 8 x bf16
typedef __attribute__((ext_vector_type(4))) float f4acc;   // 4 x f32 acc

__device__ __forceinline__ unsigned short f2bs(float f){   // f32 -> bf16 (RNE)
  unsigned u = __float_as_uint(f);
  return (unsigned short)((u + 0x7fffu + ((u >> 16) & 1u)) >> 16);
}
__device__ __forceinline__ float bs2f(unsigned short s){
  return __uint_as_float(((unsigned)s) << 16);
}

__device__ __forceinline__ void atomicMaxFloat(float* addr, float val){
  int old = __float_as_int(*addr);
  while (__int_as_float(old) < val){
    int assumed = old;
    old = atomicCAS((int*)addr, assumed, __float_as_int(val));
    if (old == assumed) break;
  }
}

// ------- setup: weights->bf16t, x->bf16, zero agg/cnt/fill/aux/..., ------
__global__ __launch_bounds__(256) void k_setup(
    const float* __restrict__ We, const float* __restrict__ W1,
    const float* __restrict__ W2, const float* __restrict__ Wg1,
    const float* __restrict__ x,
    unsigned short* __restrict__ Wet, unsigned short* __restrict__ W1t,
    unsigned short* __restrict__ W2t, unsigned short* __restrict__ Wg1t,
    unsigned short* __restrict__ xb,
    float* __restrict__ agg, int* __restrict__ cnt, int* __restrict__ fill,
    int* __restrict__ aux, float* __restrict__ gmax, float* __restrict__ denom,
    float* __restrict__ pooled)
{
  size_t i = (size_t)blockIdx.x * 256 + threadIdx.x;
  if (i < 128 * 64){ int c = (int)i >> 6, k = (int)i & 63;  Wet[i]  = f2bs(We[k * 128 + c]); }
  if (i < 256 * 128){ int n = (int)i >> 7, k = (int)i & 127; W1t[i]  = f2bs(W1[k * 256 + n]); }
  if (i < 256 * 256){ int n = (int)i >> 8, k = (int)i & 255; W2t[i]  = f2bs(W2[k * 256 + n]); }
  if (i < 128 * 256){ int n = (int)i >> 8, k = (int)i & 255; Wg1t[i] = f2bs(Wg1[k * 128 + n]); }
  if (i < (size_t)NN * IN_C / 4){
    const float4 v = ((const float4*)x)[i];
    ushort4 o;
    o.x = f2bs(v.x); o.y = f2bs(v.y); o.z = f2bs(v.z); o.w = f2bs(v.w);
    ((ushort4*)xb)[i] = o;
  }
  if (i < (size_t)NN * IN_C) agg[i] = 0.f;
  if (i < NV){ cnt[i] = 0; fill[i] = 0; }
  if (i < 256) aux[i] = 0;
  if (i < BB){ gmax[i] = -1e30f; denom[i] = 0.f; }
  if (i < BB * HID_C) pooled[i] = 0.f;
}

// ---------------- counting sort by dst: hist -> scan -> scatter ----------
__global__ __launch_bounds__(256) void k_hist(const int* __restrict__ ei,
                                              int* __restrict__ cnt){
  int e = blockIdx.x * 256 + threadIdx.x;
  if (e < EE) atomicAdd(&cnt[ei[EE + e]], 1);
}

__global__ __launch_bounds__(256) void k_scan1(const int* __restrict__ cnt,
                                               int* __restrict__ off,
                                               int* __restrict__ aux){
  __shared__ int s[256];
  int t = threadIdx.x, i = blockIdx.x * 256 + t;
  int val = cnt[i];
  s[t] = val; __syncthreads();
#pragma unroll
  for (int o = 1; o < 256; o <<= 1){
    int v = (t >= o) ? s[t - o] : 0;
    __syncthreads();
    s[t] += v;
    __syncthreads();
  }
  off[i] = s[t] - val;
  if (t == 255) aux[blockIdx.x] = s[255];
}

__global__ __launch_bounds__(256) void k_scan2(int* __restrict__ aux){
  __shared__ int s[256];
  int t = threadIdx.x;
  int val = aux[t];
  s[t] = val; __syncthreads();
#pragma unroll
  for (int o = 1; o < 256; o <<= 1){
    int v = (t >= o) ? s[t - o] : 0;
    __syncthreads();
    s[t] += v;
    __syncthreads();
  }
  aux[t] = s[t] - val;
}

__global__ __launch_bounds__(256) void k_scan3(int* __restrict__ off,
                                               const int* __restrict__ aux){
  int i = blockIdx.x * 256 + threadIdx.x;
  off[i] += aux[blockIdx.x];
}

__global__ __launch_bounds__(256) void k_scatter(const int* __restrict__ ei,
                                                 const int* __restrict__ off,
                                                 int* __restrict__ fill,
                                                 uint4* __restrict__ sorted){
  int e = blockIdx.x * 256 + threadIdx.x;
  if (e < EE){
    int s = ei[e], d = ei[EE + e];
    int pos = off[d] + atomicAdd(&fill[d], 1);
    sorted[pos] = make_uint4((unsigned)e, (unsigned)s, (unsigned)d, 0u);
  }
}

// ---------------- edge stage (unchanged from R10) ------------------------
__global__ __launch_bounds__(256, 4) void k_edge2(
    const unsigned short* __restrict__ xb, const uint4* __restrict__ sorted,
    const float* __restrict__ edge_attr,
    const unsigned short* __restrict__ Wet, const float* __restrict__ be,
    float* __restrict__ agg)
{
  __shared__ float msgS[64 * 132];
  __shared__ uint4 sE[64];
  __shared__ int runStart[66];
  __shared__ int nRunsS;
  unsigned short* eaS = (unsigned short*)msgS;

  const int tid = threadIdx.x;
  const int e0 = blockIdx.x * 64;
  if (tid < 64) sE[tid] = sorted[e0 + tid];
  __syncthreads();

  const int lane = tid & 63, wv = tid >> 6;
  const int q = lane >> 4, l15 = lane & 15;
  const int g0 = wv * 16;

  const int xrow = g0 + (lane >> 2);
  const int xc0 = (lane & 3) * 32;
  const unsigned short* xptr = xb + (size_t)((int)sE[xrow].y) * IN_C + xc0;
  uint4 xr[4];
#pragma unroll
  for (int j = 0; j < 4; ++j) xr[j] = *(const uint4*)(xptr + j * 8);

#pragma unroll
  for (int t = 0; t < 4; ++t){
    int f4 = t * 256 + tid;
    int er = f4 >> 4;
    int kk = (f4 & 15) * 4;
    int eid = (int)sE[er].x;
    const float4 v = *(const float4*)(edge_attr + (size_t)eid * ED_C + kk);
    unsigned p0 = (unsigned)f2bs(v.x) | ((unsigned)f2bs(v.y) << 16);
    unsigned p1 = (unsigned)f2bs(v.z) | ((unsigned)f2bs(v.w) << 16);
    *(uint2*)&eaS[er * 72 + kk] = make_uint2(p0, p1);
  }

  if (tid < 64){
    bool flag = (tid == 0) || ((int)sE[tid].z != (int)sE[tid - 1].z);
    unsigned long long m = __ballot(flag);
    int pre = __popcll(m & ((1ull << tid) - 1ull));
    if ((m >> tid) & 1ull) runStart[pre] = tid;
    if (tid == 0){
      int nr = __popcll(m);
      nRunsS = nr;
      runStart[nr] = 64;
    }
  }
  __syncthreads();

  f4acc acc[8];
  const f4acc zz = {0.f, 0.f, 0.f, 0.f};
#pragma unroll
  for (int nt = 0; nt < 8; ++nt) acc[nt] = zz;

#pragma unroll
  for (int ks = 0; ks < 2; ++ks){
    bfrag a = *(const bfrag*)&eaS[(g0 + l15) * 72 + ks * 32 + q * 8];
#pragma unroll
    for (int nt = 0; nt < 8; ++nt){
      int c = nt * 16 + l15;
      bfrag b = *(const bfrag*)(Wet + c * ED_C + ks * 32 + q * 8);
      acc[nt] = __builtin_amdgcn_mfma_f32_16x16x32_bf16(a, b, acc[nt], 0, 0, 0);
    }
  }

  float bev[8];
#pragma unroll
  for (int nt = 0; nt < 8; ++nt) bev[nt] = be[nt * 16 + l15];

  __syncthreads();

#pragma unroll
  for (int nt = 0; nt < 8; ++nt){
    int c = nt * 16 + l15;
#pragma unroll
    for (int r = 0; r < 4; ++r)
      msgS[(g0 + q * 4 + r) * 132 + c] = acc[nt][r] + bev[nt];
  }

  {
    float* mr = &msgS[xrow * 132 + xc0];
#pragma unroll
    for (int jj = 0; jj < 4; ++jj){
      const uint4 u = xr[jj];
      float4 w0 = *(float4*)(mr + jj * 8);
      float4 w1 = *(float4*)(mr + jj * 8 + 4);
      w0.x = fmaxf(w0.x + __uint_as_float(u.x << 16), 0.f);
      w0.y = fmaxf(w0.y + __uint_as_float(u.x & 0xffff0000u), 0.f);
      w0.z = fmaxf(w0.z + __uint_as_float(u.y << 16), 0.f);
      w0.w = fmaxf(w0.w + __uint_as_float(u.y & 0xffff0000u), 0.f);
      w1.x = fmaxf(w1.x + __uint_as_float(u.z << 16), 0.f);
      w1.y = fmaxf(w1.y + __uint_as_float(u.z & 0xffff0000u), 0.f);
      w1.z = fmaxf(w1.z + __uint_as_float(u.w << 16), 0.f);
      w1.w = fmaxf(w1.w + __uint_as_float(u.w & 0xffff0000u), 0.f);
      *(float4*)(mr + jj * 8) = w0;
      *(float4*)(mr + jj * 8 + 4) = w1;
    }
  }
  __syncthreads();

  {
    const int col = tid & 127;
    const int h = tid >> 7;
    const int nR = nRunsS;
    for (int i = h; i < nR; i += 2){
      int s = runStart[i], e = runStart[i + 1];
      int dst = (int)sE[s].z;
      float run = 0.f;
      for (int r = s; r < e; ++r) run += msgS[r * 132 + col];
      size_t a = (size_t)dst * IN_C + col;
      if (s == 0 || e == 64) atomicAdd(&agg[a], run);
      else                   agg[a] = run;
    }
  }
}

// ---------------- h0 = agg + x -> bf16 (f32 x here) ----------------
__global__ __launch_bounds__(256) void k_h0(const float* __restrict__ agg,
                                            const float* __restrict__ x,
                                            unsigned short* __restrict__ h0b){
  int i = blockIdx.x * 256 + threadIdx.x;
  if (i < NN * IN_C) h0b[i] = f2bs(agg[i] + x[i]);
}

// ---------------- MFMA GEMM with LDS-staged fragments --------------------
// out[m][c] = A[m][:K].Wt[c][:K] + bias[c]; block 64m x 128n, 4 waves 2x2.
// GATE: fused gate head -> gateOut[m] = sum_c relu(out[m][c])*Wg2[c] + bg2.
template<int K, bool RELU, bool OB16, bool GATE>
__global__ __launch_bounds__(256) void k_gemm(
    const unsigned short* __restrict__ A, const unsigned short* __restrict__ Wt,
    const float* __restrict__ bias, unsigned short* __restrict__ outb,
    int M, int Ntot,
    const float* __restrict__ Wg2, const float* __restrict__ bg2,
    float* __restrict__ gateOut)
{
  __shared__ unsigned short aS[64 * 40];
  __shared__ unsigned short bS[128 * 40];
  __shared__ float gred[2][64];
  const int tid = threadIdx.x;
  const int lane = tid & 63, wv = tid >> 6;
  const int wi = wv >> 1, wj = wv & 1;
  const int q = lane >> 4, l15 = lane & 15;
  const int mb0 = blockIdx.x * 64;
  const int nb0 = blockIdx.y * 128;
  const int arow = tid >> 2, achk = tid & 3;

  f4acc acc[2][4];
  const f4acc zz = {0.f, 0.f, 0.f, 0.f};
#pragma unroll
  for (int mt = 0; mt < 2; ++mt)
#pragma unroll
    for (int nt = 0; nt < 4; ++nt) acc[mt][nt] = zz;

  for (int ks = 0; ks < K / 32; ++ks){
    {
      int m = mb0 + arow; if (m >= M) m = M - 1;
      const uint4 v = *(const uint4*)(A + (size_t)m * K + ks * 32 + achk * 8);
      *(uint4*)&aS[arow * 40 + achk * 8] = v;
    }
#pragma unroll
    for (int i = 0; i < 2; ++i){
      int idx = i * 256 + tid;
      int row = idx >> 2, chk = idx & 3;
      const uint4 v = *(const uint4*)(Wt + (size_t)(nb0 + row) * K + ks * 32 + chk * 8);
      *(uint4*)&bS[row * 40 + chk * 8] = v;
    }
    __syncthreads();
    bfrag a[2], b[4];
#pragma unroll
    for (int mt = 0; mt < 2; ++mt)
      a[mt] = *(const bfrag*)&aS[(wi * 32 + mt * 16 + l15) * 40 + q * 8];
#pragma unroll
    for (int nt = 0; nt < 4; ++nt)
      b[nt] = *(const bfrag*)&bS[(wj * 64 + nt * 16 + l15) * 40 + q * 8];
#pragma unroll
    for (int mt = 0; mt < 2; ++mt)
#pragma unroll
      for (int nt = 0; nt < 4; ++nt)
        acc[mt][nt] = __builtin_amdgcn_mfma_f32_16x16x32_bf16(a[mt], b[nt], acc[mt][nt], 0, 0, 0);
    __syncthreads();
  }

  const int mb = mb0 + wi * 32;
  const int nb = nb0 + wj * 64;

  if (GATE){
    // fused gate head: per-row dot with Wg2 (Ntot==128, nb0==0)
    float wg2v[4];
#pragma unroll
    for (int nt = 0; nt < 4; ++nt) wg2v[nt] = Wg2[wj * 64 + nt * 16 + l15];
    float pr[2][4];
#pragma unroll
    for (int mt = 0; mt < 2; ++mt)
#pragma unroll
      for (int r = 0; r < 4; ++r) pr[mt][r] = 0.f;
#pragma unroll
    for (int nt = 0; nt < 4; ++nt){
      float bv = bias[wj * 64 + nt * 16 + l15];
#pragma unroll
      for (int mt = 0; mt < 2; ++mt)
#pragma unroll
        for (int r = 0; r < 4; ++r){
          float v = acc[mt][nt][r] + bv;
          v = v > 0.f ? v : 0.f;
          pr[mt][r] = fmaf(v, wg2v[nt], pr[mt][r]);
        }
    }
    // reduce over the 16 l15 lanes (same row, different cols)
#pragma unroll
    for (int off = 1; off < 16; off <<= 1)
#pragma unroll
      for (int mt = 0; mt < 2; ++mt)
#pragma unroll
        for (int r = 0; r < 4; ++r)
          pr[mt][r] += __shfl_xor(pr[mt][r], off);
    if (l15 == 0){
#pragma unroll
      for (int mt = 0; mt < 2; ++mt)
#pragma unroll
        for (int r = 0; r < 4; ++r)
          gred[wj][wi * 32 + mt * 16 + q * 4 + r] = pr[mt][r];
    }
    __syncthreads();
    if (tid < 64){
      int m = mb0 + tid;
      if (m < M) gateOut[m] = gred[0][tid] + gred[1][tid] + bg2[0];
    }
  } else {
#pragma unroll
    for (int nt = 0; nt < 4; ++nt){
      int c = nb + nt * 16 + l15;
      float bv = bias[c];
#pragma unroll
      for (int mt = 0; mt < 2; ++mt){
#pragma unroll
        for (int r = 0; r < 4; ++r){
          int m = mb + mt * 16 + q * 4 + r;
          if (m < M){
            float v = acc[mt][nt][r] + bv;
            if (RELU) v = v > 0.f ? v : 0.f;
            if (OB16) outb[(size_t)m * Ntot + c] = f2bs(v);
          }
        }
      }
    }
  }
}

// ---------------- segment max (wave-shuffle; 2 barriers/segment) --------
__global__ __launch_bounds__(256) void k_gmax(const float* __restrict__ gate,
                                              const int* __restrict__ batch,
                                              float* __restrict__ gmax, int nrows){
  __shared__ float wred[4];
  const int tid = threadIdx.x;
  const int n0 = blockIdx.x * 256;
  const int n = n0 + tid;
  const int nlast = (n0 + 255 < nrows) ? n0 + 255 : nrows - 1;
  const int bmin = batch[n0], bmax = batch[nlast];
  const int lane = tid & 63, wv = tid >> 6;
  float val = -3e38f; int b = bmax;
  if (n < nrows){ b = batch[n]; val = gate[n]; }
  for (int bb = bmin; bb <= bmax; ++bb){
    float v = (b == bb) ? val : -3e38f;
#pragma unroll
    for (int off = 1; off < 64; off <<= 1) v = fmaxf(v, __shfl_xor(v, off));
    if (lane == 0) wred[wv] = v;
    __syncthreads();
    if (tid == 0){
      float m = fmaxf(fmaxf(wred[0], wred[1]), fmaxf(wred[2], wred[3]));
      if (m > -1e37f) atomicMaxFloat(&gmax[bb], m);
    }
    __syncthreads();
  }
}

// ---------------- a = exp(gate - gmax[b]); denom[b] += a ----------------
__global__ __launch_bounds__(256) void k_expsum(const float* __restrict__ gate,
                                                const int* __restrict__ batch,
                                                const float* __restrict__ gmax,
                                                float* __restrict__ aexp,
                                                float* __restrict__ denom, int nrows){
  __shared__ float wred[4];
  const int tid = threadIdx.x;
  const int n0 = blockIdx.x * 256;
  const int n = n0 + tid;
  const int nlast = (n0 + 255 < nrows) ? n0 + 255 : nrows - 1;
  const int bmin = batch[n0], bmax = batch[nlast];
  const int lane = tid & 63, wv = tid >> 6;
  float val = 0.f; int b = bmax;
  if (n < nrows){
    b = batch[n];
    val = expf(gate[n] - gmax[b]);
    aexp[n] = val;
  }
  for (int bb = bmin; bb <= bmax; ++bb){
    float v = (b == bb) ? val : 0.f;
#pragma unroll
    for (int off = 1; off < 64; off <<= 1) v += __shfl_xor(v, off);
    if (lane == 0) wred[wv] = v;
    __syncthreads();
    if (tid == 0){
      float s = wred[0] + wred[1] + wred[2] + wred[3];
      if (s != 0.f) atomicAdd(&denom[bb], s);
    }
    __syncthreads();
  }
}

// ---------------- pooled[b] += (a/denom[b]) * h2[n]  (32-row chunks) -----
__global__ __launch_bounds__(256) void k_pool(const unsigned short* __restrict__ h2b,
                                              const float* __restrict__ aexp,
                                              const float* __restrict__ denom,
                                              const int* __restrict__ batch,
                                              float* __restrict__ pooled, int nrows){
  const int c = threadIdx.x;
  const int n0 = blockIdx.x * 32;
  int n1 = n0 + 32; if (n1 > nrows) n1 = nrows;
  if (n0 >= nrows) return;
  float acc = 0.f;
  int curb = batch[n0];
  for (int n = n0; n < n1; ++n){
    int b = batch[n];
    if (b != curb){
      atomicAdd(&pooled[(size_t)curb * HID_C + c], acc);
      acc = 0.f; curb = b;
    }
    float wgt = aexp[n] / denom[b];
    acc = fmaf(wgt, bs2f(h2b[(size_t)n * HID_C + c]), acc);
  }
  atomicAdd(&pooled[(size_t)curb * HID_C + c], acc);
}

// ---------------- head: logits = pooled @ Wh + bh ----------------
__global__ __launch_bounds__(256) void k_head(const float* __restrict__ pooled,
                                              const float* __restrict__ Wh,
                                              const float* __restrict__ bh,
                                              float* __restrict__ out_logits,
                                              float* __restrict__ out_pooled){
  __shared__ float p[HID_C];
  const int b = blockIdx.x, t = threadIdx.x;
  float pv = pooled[(size_t)b * HID_C + t];
  p[t] = pv;
  out_pooled[(size_t)b * HID_C + t] = pv;
  __syncthreads();
  for (int c = t; c < KK; c += 256){
    float acc = bh[c];
#pragma unroll 8
    for (int k = 0; k < HID_C; ++k)
      acc = fmaf(p[k], Wh[k * KK + c], acc);
    out_logits[(size_t)b * KK + c] = acc;
  }
}

extern "C" void kernel_launch(void* const* d_in, const int* in_sizes, int n_in,
                              void* d_out, int out_size, void* d_ws, size_t ws_size,
                              hipStream_t stream) {
  const float* x   = (const float*)d_in[0];
  const int*   ei  = (const int*)d_in[1];
  const float* ea  = (const float*)d_in[2];
  const int*   batch = (const int*)d_in[3];
  const float* We  = (const float*)d_in[4];
  const float* be  = (const float*)d_in[5];
  const float* W1  = (const float*)d_in[6];
  const float* b1  = (const float*)d_in[7];
  const float* W2  = (const float*)d_in[8];
  const float* b2  = (const float*)d_in[9];
  const float* Wg1 = (const float*)d_in[10];
  const float* bg1 = (const float*)d_in[11];
  const float* Wg2 = (const float*)d_in[12];
  const float* bg2 = (const float*)d_in[13];
  const float* Wh  = (const float*)d_in[14];
  const float* bh  = (const float*)d_in[15];

  float* out_logits = (float*)d_out;
  float* out_pooled = out_logits + (size_t)BB * KK;

  // ws layout: f32 region | h0b | h1b (aliased by sort scratch) | h2b |
  // weights | xb
  float* agg    = (float*)d_ws;                    // N*128
  float* gate   = agg   + (size_t)NN * IN_C;       // N
  float* aexp   = gate  + NN;                      // N
  float* gmax   = aexp  + NN;                      // B
  float* denom  = gmax  + BB;                      // B
  float* pooled = denom + BB;                      // B*256
  float* fend   = pooled + (size_t)BB * HID_C;     // 16B-aligned
  unsigned short* h0b  = (unsigned short*)fend;    // N*128 bf16
  unsigned short* h1b  = h0b + (size_t)NN * IN_C;  // N*256 bf16 (25.6MB)
  unsigned short* h2b  = h1b + (size_t)NN * HID_C; // N*256 bf16
  unsigned short* Wet  = h2b + (size_t)NN * HID_C; // 128*64
  unsigned short* W1t  = Wet + 128 * 64;
  unsigned short* W2t  = W1t + 256 * 128;
  unsigned short* Wg1t = W2t + 256 * 256;
  unsigned short* xb   = Wg1t + 128 * 256;         // N*128 bf16 (12.8MB)
  // sort scratch aliases h1b region (dead until gemm1): 12.8MB + 0.6MB < 25.6MB
  uint4* sorted = (uint4*)h1b;                     // EE * 16B
  int* cnt  = (int*)(sorted + EE);                 // NV
  int* off  = cnt + NV;                            // NV
  int* fill = off + NV;                            // NV
  int* aux  = fill + NV;                           // 256

  k_setup<<<(NN * IN_C + 255) / 256, 256, 0, stream>>>(
      We, W1, W2, Wg1, x, Wet, W1t, W2t, Wg1t, xb,
      agg, cnt, fill, aux, gmax, denom, pooled);
  // counting sort by dst
  k_hist   <<<(EE + 255) / 256, 256, 0, stream>>>(ei, cnt);
  k_scan1  <<<NV / 256, 256, 0, stream>>>(cnt, off, aux);
  k_scan2  <<<1, 256, 0, stream>>>(aux);
  k_scan3  <<<NV / 256, 256, 0, stream>>>(off, aux);
  k_scatter<<<(EE + 255) / 256, 256, 0, stream>>>(ei, off, fill, sorted);
  // edge projection + message + run-list segmented-reduce scatter
  k_edge2<<<EE / 64, 256, 0, stream>>>(xb, sorted, ea, Wet, be, agg);
  k_h0<<<(NN * IN_C + 255) / 256, 256, 0, stream>>>(agg, x, h0b);
  // MLP GEMMs + fused gate (sort scratch dead from here; h1b reused)
  k_gemm<128, true,  true,  false><<<dim3(782, 2), 256, 0, stream>>>(
      h0b, W1t, b1, h1b, NN, HID_C, (const float*)0, (const float*)0, (float*)0);
  k_gemm<256, false, true,  false><<<dim3(782, 2), 256, 0, stream>>>(
      h1b, W2t, b2, h2b, NN, HID_C, (const float*)0, (const float*)0, (float*)0);
  k_gemm<256, true,  false, true ><<<dim3(782, 1), 256, 0, stream>>>(
      h2b, Wg1t, bg1, (unsigned short*)0, NN, G1_C, Wg2, bg2, gate);
  k_gmax  <<<(NN + 255) / 256, 256, 0, stream>>>(gate, batch, gmax, NN);
  k_expsum<<<(NN + 255) / 256, 256, 0, stream>>>(gate, batch, gmax, aexp, denom, NN);
  k_pool  <<<(NN + 31) / 32, 256, 0, stream>>>(h2b, aexp, denom, batch, pooled, NN);
  k_head<<<BB, 256, 0, stream>>>(pooled, Wh, bh, out_logits, out_pooled);
}